// Round 1
// baseline (218.541 us; speedup 1.0000x reference)
//
#include <hip/hip_runtime.h>

typedef __bf16 bf16x8 __attribute__((ext_vector_type(8)));
typedef float f32x4 __attribute__((ext_vector_type(4)));
typedef unsigned short ushort8 __attribute__((ext_vector_type(8)));

#define DMODEL 1024
#define HEADS 16
#define DH 64
#define BATCH 2
#define SEQ 2048

__device__ __forceinline__ unsigned short f2bf(float f) {
  unsigned int u = __builtin_bit_cast(unsigned int, f);
  u += 0x7FFFu + ((u >> 16) & 1u);
  return (unsigned short)(u >> 16);
}

// ---------------- fp32 -> bf16 conversion (8 elems/thread) ----------------
__global__ void cvt8(const float* __restrict__ src, unsigned short* __restrict__ dst, int n8) {
  int i = blockIdx.x * 256 + threadIdx.x;
  if (i >= n8) return;
  const float4* s4 = (const float4*)src;
  float4 a = s4[(size_t)i * 2];
  float4 b = s4[(size_t)i * 2 + 1];
  ushort8 o;
  o[0] = f2bf(a.x); o[1] = f2bf(a.y); o[2] = f2bf(a.z); o[3] = f2bf(a.w);
  o[4] = f2bf(b.x); o[5] = f2bf(b.y); o[6] = f2bf(b.z); o[7] = f2bf(b.w);
  *(ushort8*)(dst + (size_t)i * 8) = o;
}

// ---------------- GEMM: C[M,N] = A[M,K] @ B[N,K]^T (bf16 in, f32 acc) -----
// 128x128 tile, BK=32, 256 threads (4 waves as 2x2, each wave 64x64).
// MODE 0: QKV projection epilogue (bf16 out, permuted layouts)
// MODE 1: fp32 row-major out
template<int MODE>
__global__ __launch_bounds__(256) void gemm_bt(
    const unsigned short* __restrict__ A, const unsigned short* __restrict__ Bm,
    int K,
    unsigned short* __restrict__ qb, unsigned short* __restrict__ kb,
    unsigned short* __restrict__ vt, float* __restrict__ fout)
{
  __shared__ alignas(16) unsigned short sA[128 * 32];
  __shared__ alignas(16) unsigned short sB[128 * 32];
  const int tid = threadIdx.x;
  const int lane = tid & 63, wave = tid >> 6;
  const int wm = wave >> 1, wn = wave & 1;
  const int l15 = lane & 15, lg = lane >> 4;
  const int row0 = blockIdx.y * 128, col0 = blockIdx.x * 128;

  f32x4 acc[4][4] = {};

  for (int k0 = 0; k0 < K; k0 += 32) {
#pragma unroll
    for (int i = 0; i < 2; ++i) {
      int flat = i * 256 + tid;
      int r = flat >> 2, cs = (flat & 3) * 8;
      __builtin_amdgcn_global_load_lds(
          (const __attribute__((address_space(1))) void*)(A + (size_t)(row0 + r) * K + k0 + cs),
          (__attribute__((address_space(3))) void*)(sA + flat * 8), 16, 0, 0);
      __builtin_amdgcn_global_load_lds(
          (const __attribute__((address_space(1))) void*)(Bm + (size_t)(col0 + r) * K + k0 + cs),
          (__attribute__((address_space(3))) void*)(sB + flat * 8), 16, 0, 0);
    }
    __syncthreads();
    bf16x8 af[4], bf[4];
#pragma unroll
    for (int m = 0; m < 4; ++m)
      af[m] = *(const bf16x8*)&sA[(wm * 64 + m * 16 + l15) * 32 + lg * 8];
#pragma unroll
    for (int n = 0; n < 4; ++n)
      bf[n] = *(const bf16x8*)&sB[(wn * 64 + n * 16 + l15) * 32 + lg * 8];
#pragma unroll
    for (int m = 0; m < 4; ++m)
#pragma unroll
      for (int n = 0; n < 4; ++n)
        acc[m][n] = __builtin_amdgcn_mfma_f32_16x16x32_bf16(af[m], bf[n], acc[m][n], 0, 0, 0);
    __syncthreads();
  }

  // epilogue. C/D layout: col = lane&15, row = (lane>>4)*4 + reg  [m89]
#pragma unroll
  for (int m = 0; m < 4; ++m) {
#pragma unroll
    for (int n = 0; n < 4; ++n) {
      const int c = col0 + wn * 64 + n * 16 + l15;
#pragma unroll
      for (int reg = 0; reg < 4; ++reg) {
        const int r = row0 + wm * 64 + m * 16 + lg * 4 + reg;
        float v = acc[m][n][reg];
        if (MODE == 0) {
          const int which = c >> 10, c2 = c & 1023;
          const int h = c2 >> 6, d = c2 & 63;
          const int b = r >> 11, s = r & 2047;
          const unsigned short bv = f2bf(v);
          if (which == 0)
            qb[(((size_t)(b * HEADS + h)) * SEQ + s) * DH + d] = bv;
          else if (which == 1)
            kb[(((size_t)(b * HEADS + h)) * SEQ + s) * DH + d] = bv;
          else
            vt[(((size_t)(b * HEADS + h)) * DH + d) * SEQ + s] = bv;
        } else {
          fout[(size_t)r * DMODEL + c] = v;
        }
      }
    }
  }
}

// ---------------- causal flash attention ----------------------------------
// grid: (S/64, B*H). 256 threads = 4 waves; wave w owns q rows q0+w*16..+15.
// Swapped QK^T: stacc = mfma(K, Q) -> S^T, lane owns q = lane&15.
__global__ __launch_bounds__(256) void attn_fwd(
    const unsigned short* __restrict__ q, const unsigned short* __restrict__ k,
    const unsigned short* __restrict__ vt, unsigned short* __restrict__ attn)
{
  __shared__ alignas(16) unsigned short sK[32 * 64];   // [kv][d]
  __shared__ alignas(16) unsigned short sVt[64 * 32];  // [d][kv]
  __shared__ alignas(16) unsigned short sP[4][16 * 32]; // per-wave [q][kv]
  const int tid = threadIdx.x, lane = tid & 63, wave = tid >> 6;
  const int l15 = lane & 15, lg = lane >> 4;
  const int bh = blockIdx.y;
  const int q0 = blockIdx.x * 64;
  const int qw = q0 + wave * 16;
  const int qglane = qw + l15;

  // Q fragments in registers (reused every tile)
  const unsigned short* qptr = q + (((size_t)bh) * SEQ + qw + l15) * DH + lg * 8;
  const bf16x8 qf0 = *(const bf16x8*)qptr;
  const bf16x8 qf1 = *(const bf16x8*)(qptr + 32);

  f32x4 o[4] = {};
  float m_r = -1e30f, l_r = 0.0f;

  const int nt = (q0 + 64) >> 5;  // kv tiles of 32, causal bound
  for (int t = 0; t < nt; ++t) {
    const int kv0 = t * 32;
    {
      int r = tid >> 3, cs = (tid & 7) * 8;
      __builtin_amdgcn_global_load_lds(
          (const __attribute__((address_space(1))) void*)(k + (((size_t)bh) * SEQ + kv0 + r) * DH + cs),
          (__attribute__((address_space(3))) void*)(sK + tid * 8), 16, 0, 0);
      int r2 = tid >> 2, cs2 = (tid & 3) * 8;
      __builtin_amdgcn_global_load_lds(
          (const __attribute__((address_space(1))) void*)(vt + (((size_t)bh) * DH + r2) * SEQ + kv0 + cs2),
          (__attribute__((address_space(3))) void*)(sVt + tid * 8), 16, 0, 0);
    }
    __syncthreads();

    if (kv0 <= qw + 15) {  // tile not fully masked for this wave
      // S^T fragments: rows = kv (n*16 + lg*4 + reg), col = q (l15)
      f32x4 st0 = {}, st1 = {};
      {
        bf16x8 kf;
        kf = *(const bf16x8*)&sK[(l15) * 64 + lg * 8];
        st0 = __builtin_amdgcn_mfma_f32_16x16x32_bf16(kf, qf0, st0, 0, 0, 0);
        kf = *(const bf16x8*)&sK[(l15) * 64 + 32 + lg * 8];
        st0 = __builtin_amdgcn_mfma_f32_16x16x32_bf16(kf, qf1, st0, 0, 0, 0);
        kf = *(const bf16x8*)&sK[(16 + l15) * 64 + lg * 8];
        st1 = __builtin_amdgcn_mfma_f32_16x16x32_bf16(kf, qf0, st1, 0, 0, 0);
        kf = *(const bf16x8*)&sK[(16 + l15) * 64 + 32 + lg * 8];
        st1 = __builtin_amdgcn_mfma_f32_16x16x32_bf16(kf, qf1, st1, 0, 0, 0);
      }

      float p[8];
      float mx = -1e30f;
#pragma unroll
      for (int n = 0; n < 2; ++n) {
#pragma unroll
        for (int reg = 0; reg < 4; ++reg) {
          const int kvg = kv0 + n * 16 + lg * 4 + reg;
          float v = (n ? st1[reg] : st0[reg]) * 0.125f;
          v = (kvg <= qglane) ? v : -1e30f;
          p[n * 4 + reg] = v;
          mx = fmaxf(mx, v);
        }
      }
      mx = fmaxf(mx, __shfl_xor(mx, 16));
      mx = fmaxf(mx, __shfl_xor(mx, 32));
      const float m_new = fmaxf(m_r, mx);
      const float alpha = __expf(m_r - m_new);
      float psum = 0.f;
#pragma unroll
      for (int i = 0; i < 8; ++i) {
        const float e = __expf(p[i] - m_new);
        p[i] = e;
        psum += e;
      }
      psum += __shfl_xor(psum, 16);
      psum += __shfl_xor(psum, 32);
      l_r = l_r * alpha + psum;
      m_r = m_new;

      // rescale O: O rows are q = lg*4+reg, alpha lives at lane q (group 0)
#pragma unroll
      for (int reg = 0; reg < 4; ++reg) {
        const float ab = __shfl(alpha, lg * 4 + reg);
        o[0][reg] *= ab; o[1][reg] *= ab; o[2][reg] *= ab; o[3][reg] *= ab;
      }

      // redistribute P (S^T C-layout) -> A-fragment layout via per-wave LDS
#pragma unroll
      for (int n = 0; n < 2; ++n)
#pragma unroll
        for (int reg = 0; reg < 4; ++reg)
          sP[wave][l15 * 32 + n * 16 + lg * 4 + reg] = f2bf(p[n * 4 + reg]);
      asm volatile("s_waitcnt lgkmcnt(0)" ::: "memory");
      __builtin_amdgcn_sched_barrier(0);
      const bf16x8 pf = *(const bf16x8*)&sP[wave][l15 * 32 + lg * 8];
#pragma unroll
      for (int d = 0; d < 4; ++d) {
        const bf16x8 vf = *(const bf16x8*)&sVt[(d * 16 + l15) * 32 + lg * 8];
        o[d] = __builtin_amdgcn_mfma_f32_16x16x32_bf16(pf, vf, o[d], 0, 0, 0);
      }
    }
    __syncthreads();
  }

  // epilogue: divide by l, write bf16 attn_out [b, s, h*64+d]
  const int b = bh >> 4, h = bh & 15;
#pragma unroll
  for (int reg = 0; reg < 4; ++reg) {
    const float lb = __shfl(l_r, lg * 4 + reg);
    const float inv = 1.0f / lb;
    const int s = qw + lg * 4 + reg;
#pragma unroll
    for (int d = 0; d < 4; ++d) {
      attn[((size_t)b * SEQ + s) * DMODEL + h * DH + d * 16 + l15] =
          f2bf(o[d][reg] * inv);
    }
  }
}

// ---------------------------------------------------------------------------
extern "C" void kernel_launch(void* const* d_in, const int* in_sizes, int n_in,
                              void* d_out, int out_size, void* d_ws, size_t ws_size,
                              hipStream_t stream) {
  const float* x  = (const float*)d_in[0];
  // d_in[1] = causal mask (tril) — structure known, not read
  const float* Wq = (const float*)d_in[2];
  const float* Wk = (const float*)d_in[3];
  const float* Wv = (const float*)d_in[4];
  const float* Wo = (const float*)d_in[5];
  float* out = (float*)d_out;

  unsigned short* ws = (unsigned short*)d_ws;
  const size_t MEL = (size_t)1024 * 1024;
  unsigned short* xb   = ws;            // 4M elems
  unsigned short* wqkv = xb + 4 * MEL;  // 3M (Wq|Wk|Wv rows)
  unsigned short* wo   = wqkv + 3 * MEL;// 1M
  unsigned short* qb   = wo + MEL;      // 4M  [bh][s][64]
  unsigned short* kb   = qb + 4 * MEL;  // 4M  [bh][s][64]
  unsigned short* vtb  = kb + 4 * MEL;  // 4M  [bh][64][s]
  unsigned short* attn = vtb + 4 * MEL; // 4M  [b*s][1024]

  cvt8<<<2048, 256, 0, stream>>>(x, xb, 524288);
  cvt8<<<512, 256, 0, stream>>>(Wq, wqkv, 131072);
  cvt8<<<512, 256, 0, stream>>>(Wk, wqkv + MEL, 131072);
  cvt8<<<512, 256, 0, stream>>>(Wv, wqkv + 2 * MEL, 131072);
  cvt8<<<512, 256, 0, stream>>>(Wo, wo, 131072);

  dim3 g1(3072 / 128, 4096 / 128);  // QKV projection
  gemm_bt<0><<<g1, 256, 0, stream>>>(xb, wqkv, DMODEL, qb, kb, vtb, nullptr);

  dim3 g2(SEQ / 64, BATCH * HEADS);  // attention
  attn_fwd<<<g2, 256, 0, stream>>>(qb, kb, vtb, attn);

  dim3 g3(1024 / 128, 4096 / 128);  // output projection
  gemm_bt<1><<<g3, 256, 0, stream>>>(attn, wo, DMODEL, nullptr, nullptr, nullptr, out);
}

// Round 2
// 208.827 us; speedup vs baseline: 1.0465x; 1.0465x over previous
//
#include <hip/hip_runtime.h>

typedef __bf16 bf16x8 __attribute__((ext_vector_type(8)));
typedef float f32x4 __attribute__((ext_vector_type(4)));
typedef unsigned short ushort8 __attribute__((ext_vector_type(8)));

#define DMODEL 1024
#define HEADS 16
#define DH 64
#define BATCH 2
#define SEQ 2048

__device__ __forceinline__ unsigned short f2bf(float f) {
  unsigned int u = __builtin_bit_cast(unsigned int, f);
  u += 0x7FFFu + ((u >> 16) & 1u);
  return (unsigned short)(u >> 16);
}

// ---------------- fp32 -> bf16 conversion (8 elems/thread) ----------------
__global__ void cvt8(const float* __restrict__ src, unsigned short* __restrict__ dst, int n8) {
  int i = blockIdx.x * 256 + threadIdx.x;
  if (i >= n8) return;
  const float4* s4 = (const float4*)src;
  float4 a = s4[(size_t)i * 2];
  float4 b = s4[(size_t)i * 2 + 1];
  ushort8 o;
  o[0] = f2bf(a.x); o[1] = f2bf(a.y); o[2] = f2bf(a.z); o[3] = f2bf(a.w);
  o[4] = f2bf(b.x); o[5] = f2bf(b.y); o[6] = f2bf(b.z); o[7] = f2bf(b.w);
  *(ushort8*)(dst + (size_t)i * 8) = o;
}

// ---------------- GEMM: C[M,N] = A[M,K] @ B[N,K]^T (bf16 in, f32 acc) -----
template<int MODE>
__global__ __launch_bounds__(256) void gemm_bt(
    const unsigned short* __restrict__ A, const unsigned short* __restrict__ Bm,
    int K,
    unsigned short* __restrict__ qb, unsigned short* __restrict__ kb,
    unsigned short* __restrict__ vt, float* __restrict__ fout)
{
  __shared__ alignas(16) unsigned short sA[128 * 32];
  __shared__ alignas(16) unsigned short sB[128 * 32];
  const int tid = threadIdx.x;
  const int lane = tid & 63, wave = tid >> 6;
  const int wm = wave >> 1, wn = wave & 1;
  const int l15 = lane & 15, lg = lane >> 4;
  const int row0 = blockIdx.y * 128, col0 = blockIdx.x * 128;

  f32x4 acc[4][4] = {};

  for (int k0 = 0; k0 < K; k0 += 32) {
#pragma unroll
    for (int i = 0; i < 2; ++i) {
      int flat = i * 256 + tid;
      int r = flat >> 2, cs = (flat & 3) * 8;
      __builtin_amdgcn_global_load_lds(
          (const __attribute__((address_space(1))) void*)(A + (size_t)(row0 + r) * K + k0 + cs),
          (__attribute__((address_space(3))) void*)(sA + flat * 8), 16, 0, 0);
      __builtin_amdgcn_global_load_lds(
          (const __attribute__((address_space(1))) void*)(Bm + (size_t)(col0 + r) * K + k0 + cs),
          (__attribute__((address_space(3))) void*)(sB + flat * 8), 16, 0, 0);
    }
    __syncthreads();
    bf16x8 af[4], bfr[4];
#pragma unroll
    for (int m = 0; m < 4; ++m)
      af[m] = *(const bf16x8*)&sA[(wm * 64 + m * 16 + l15) * 32 + lg * 8];
#pragma unroll
    for (int n = 0; n < 4; ++n)
      bfr[n] = *(const bf16x8*)&sB[(wn * 64 + n * 16 + l15) * 32 + lg * 8];
#pragma unroll
    for (int m = 0; m < 4; ++m)
#pragma unroll
      for (int n = 0; n < 4; ++n)
        acc[m][n] = __builtin_amdgcn_mfma_f32_16x16x32_bf16(af[m], bfr[n], acc[m][n], 0, 0, 0);
    __syncthreads();
  }

  // epilogue. C/D layout: col = lane&15, row = (lane>>4)*4 + reg  [m89]
#pragma unroll
  for (int m = 0; m < 4; ++m) {
#pragma unroll
    for (int n = 0; n < 4; ++n) {
      const int c = col0 + wn * 64 + n * 16 + l15;
#pragma unroll
      for (int reg = 0; reg < 4; ++reg) {
        const int r = row0 + wm * 64 + m * 16 + lg * 4 + reg;
        float v = acc[m][n][reg];
        if (MODE == 0) {
          const int which = c >> 10, c2 = c & 1023;
          const int h = c2 >> 6, d = c2 & 63;
          const int b = r >> 11, s = r & 2047;
          const unsigned short bv = f2bf(v);
          if (which == 0)
            qb[(((size_t)(b * HEADS + h)) * SEQ + s) * DH + d] = bv;
          else if (which == 1)
            kb[(((size_t)(b * HEADS + h)) * SEQ + s) * DH + d] = bv;
          else
            vt[(((size_t)(b * HEADS + h)) * DH + d) * SEQ + s] = bv;
        } else {
          fout[(size_t)r * DMODEL + c] = v;
        }
      }
    }
  }
}

// ---------------- causal flash attention (rewritten) -----------------------
// grid: (16, B*H), 256 threads = 4 waves. Block owns 128 q rows
// (q0 = (15-bx)*128, long blocks dispatched first). Wave owns 32 q rows.
// KVBLK = 64, double-buffered K and V^T tiles in LDS, staged via
// global_load_lds with PRE-SWIZZLED global source (chunk ^= row&7) so the
// swizzled ds_read_b128 fragment reads are bank-conflict-free.
// Swapped QK^T: st = mfma(K, Q) -> S^T, lane owns q = qt*16 + (lane&15).
__global__ __launch_bounds__(256) void attn_fwd(
    const unsigned short* __restrict__ q, const unsigned short* __restrict__ k,
    const unsigned short* __restrict__ vt, unsigned short* __restrict__ attn)
{
  __shared__ alignas(16) unsigned short sK[2][64 * 64];  // [kv][d], swizzled
  __shared__ alignas(16) unsigned short sV[2][64 * 64];  // [d][kv], swizzled
  __shared__ alignas(16) unsigned short sP[4][32 * 64];  // per-wave, XOR (q&7)<<4

  const int tid = threadIdx.x, lane = tid & 63, wave = tid >> 6;
  const int l15 = lane & 15, lg = lane >> 4;
  const int bh = blockIdx.y;
  const int q0 = ((int)gridDim.x - 1 - (int)blockIdx.x) * 128;
  const int qw = q0 + wave * 32;

  const unsigned short* qg = q + ((size_t)bh * SEQ) * DH;
  const unsigned short* kg = k + ((size_t)bh * SEQ) * DH;
  const unsigned short* vg = vt + ((size_t)bh * DH) * SEQ;

  // Q fragments in registers: qf[qt][ks], q = qw+qt*16+l15, d = ks*32+lg*8
  bf16x8 qf[2][2];
#pragma unroll
  for (int qt = 0; qt < 2; ++qt)
#pragma unroll
    for (int ks = 0; ks < 2; ++ks)
      qf[qt][ks] = *(const bf16x8*)(qg + (size_t)(qw + qt * 16 + l15) * DH + ks * 32 + lg * 8);

  f32x4 O[2][4] = {};
  float m_r[2] = {-1e30f, -1e30f}, l_r[2] = {0.f, 0.f};

  const int nt = q0 / 64 + 2;

  auto stage = [&](int bi, int kv0) {
#pragma unroll
    for (int ph = 0; ph < 2; ++ph) {
      const int flat = ph * 256 + tid;
      const int row = flat >> 3;
      const int c = (flat & 7) ^ (row & 7);
      __builtin_amdgcn_global_load_lds(
          (const __attribute__((address_space(1))) void*)(kg + (size_t)(kv0 + row) * DH + c * 8),
          (__attribute__((address_space(3))) void*)(&sK[bi][flat * 8]), 16, 0, 0);
      __builtin_amdgcn_global_load_lds(
          (const __attribute__((address_space(1))) void*)(vg + (size_t)row * SEQ + kv0 + c * 8),
          (__attribute__((address_space(3))) void*)(&sV[bi][flat * 8]), 16, 0, 0);
    }
  };

  stage(0, 0);
  __syncthreads();

  const float CSC = 0.18033688011112042f;  // 0.125 * log2(e)
  const float THR = 44.3614195558365f;     // 8 / CSC

  for (int t = 0; t < nt; ++t) {
    const int cur = t & 1;
    const int kv0 = t * 64;
    if (t + 1 < nt) stage(cur ^ 1, kv0 + 64);

    if (kv0 <= qw + 31) {
      // ---- QK^T: st[kt][qt], rows kv = kv0+kt*16+lg*4+r, col q = qt*16+l15
      f32x4 st[4][2] = {};
      const char* sKb = (const char*)&sK[cur][0];
      __builtin_amdgcn_s_setprio(1);
#pragma unroll
      for (int kt = 0; kt < 4; ++kt) {
        const int row = kt * 16 + l15;
        const bf16x8 kf0 = *(const bf16x8*)(sKb + row * 128 + ((lg ^ (row & 7)) * 16));
        const bf16x8 kf1 = *(const bf16x8*)(sKb + row * 128 + (((4 + lg) ^ (row & 7)) * 16));
        st[kt][0] = __builtin_amdgcn_mfma_f32_16x16x32_bf16(kf0, qf[0][0], st[kt][0], 0, 0, 0);
        st[kt][0] = __builtin_amdgcn_mfma_f32_16x16x32_bf16(kf1, qf[0][1], st[kt][0], 0, 0, 0);
        st[kt][1] = __builtin_amdgcn_mfma_f32_16x16x32_bf16(kf0, qf[1][0], st[kt][1], 0, 0, 0);
        st[kt][1] = __builtin_amdgcn_mfma_f32_16x16x32_bf16(kf1, qf[1][1], st[kt][1], 0, 0, 0);
      }
      __builtin_amdgcn_s_setprio(0);

      // ---- mask + max
      const bool needmask = (kv0 + 63 > qw);
      float pmax[2];
#pragma unroll
      for (int qt = 0; qt < 2; ++qt) {
        float mx = -1e30f;
#pragma unroll
        for (int kt = 0; kt < 4; ++kt)
#pragma unroll
          for (int r = 0; r < 4; ++r) {
            float v = st[kt][qt][r];
            if (needmask) {
              const int kv = kv0 + kt * 16 + lg * 4 + r;
              const int qgl = qw + qt * 16 + l15;
              v = (kv <= qgl) ? v : -1e30f;
              st[kt][qt][r] = v;
            }
            mx = fmaxf(mx, v);
          }
        mx = fmaxf(mx, __shfl_xor(mx, 16));
        mx = fmaxf(mx, __shfl_xor(mx, 32));
        pmax[qt] = mx;
      }

      // ---- defer-max (T13): rescale only when max grew past threshold
      const bool defer = (pmax[0] - m_r[0] <= THR) && (pmax[1] - m_r[1] <= THR);
      if (!__all(defer)) {
        float al[2];
#pragma unroll
        for (int qt = 0; qt < 2; ++qt) {
          const float mn = fmaxf(m_r[qt], pmax[qt]);
          al[qt] = exp2f((m_r[qt] - mn) * CSC);
          l_r[qt] *= al[qt];
          m_r[qt] = mn;
        }
#pragma unroll
        for (int r = 0; r < 4; ++r) {
          const float a0 = __shfl(al[0], lg * 4 + r);
          const float a1 = __shfl(al[1], lg * 4 + r);
#pragma unroll
          for (int dt = 0; dt < 4; ++dt) {
            O[0][dt][r] *= a0;
            O[1][dt][r] *= a1;
          }
        }
      }

      // ---- exp, row-sum, pack P -> per-wave swizzled LDS
      unsigned short* sPw = &sP[wave][0];
#pragma unroll
      for (int qt = 0; qt < 2; ++qt) {
        float ps = 0.f;
        const int qlocal = qt * 16 + l15;
#pragma unroll
        for (int kt = 0; kt < 4; ++kt) {
          float e0 = exp2f((st[kt][qt][0] - m_r[qt]) * CSC);
          float e1 = exp2f((st[kt][qt][1] - m_r[qt]) * CSC);
          float e2 = exp2f((st[kt][qt][2] - m_r[qt]) * CSC);
          float e3 = exp2f((st[kt][qt][3] - m_r[qt]) * CSC);
          ps += (e0 + e1) + (e2 + e3);
          uint2 w;
          w.x = (unsigned)f2bf(e0) | ((unsigned)f2bf(e1) << 16);
          w.y = (unsigned)f2bf(e2) | ((unsigned)f2bf(e3) << 16);
          const int byteoff = (qlocal * 128 + kt * 32 + lg * 8) ^ ((l15 & 7) << 4);
          *(uint2*)((char*)sPw + byteoff) = w;
        }
        ps += __shfl_xor(ps, 16);
        ps += __shfl_xor(ps, 32);
        l_r[qt] += ps;
      }
      asm volatile("s_waitcnt lgkmcnt(0)" ::: "memory");
      __builtin_amdgcn_sched_barrier(0);

      // ---- PV: O[qt][dt] += P[q][kv] * V^T[d][kv]
      const char* sVb = (const char*)&sV[cur][0];
      __builtin_amdgcn_s_setprio(1);
#pragma unroll
      for (int ks = 0; ks < 2; ++ks) {
        const bf16x8 pf0 = *(const bf16x8*)((const char*)sPw +
            (((0 * 16 + l15) * 128 + ks * 64 + lg * 16) ^ ((l15 & 7) << 4)));
        const bf16x8 pf1 = *(const bf16x8*)((const char*)sPw +
            (((1 * 16 + l15) * 128 + ks * 64 + lg * 16) ^ ((l15 & 7) << 4)));
#pragma unroll
        for (int dt = 0; dt < 4; ++dt) {
          const int row = dt * 16 + l15;
          const bf16x8 vf = *(const bf16x8*)(sVb + row * 128 + (((ks * 4 + lg) ^ (row & 7)) * 16));
          O[0][dt] = __builtin_amdgcn_mfma_f32_16x16x32_bf16(pf0, vf, O[0][dt], 0, 0, 0);
          O[1][dt] = __builtin_amdgcn_mfma_f32_16x16x32_bf16(pf1, vf, O[1][dt], 0, 0, 0);
        }
      }
      __builtin_amdgcn_s_setprio(0);
    }
    __syncthreads();
  }

  // ---- epilogue: divide by l, write bf16 attn_out [b, s, h*64+d]
  const int b = bh >> 4, h = bh & 15;
#pragma unroll
  for (int qt = 0; qt < 2; ++qt) {
    const float inv = 1.0f / l_r[qt];
#pragma unroll
    for (int r = 0; r < 4; ++r) {
      const float iv = __shfl(inv, lg * 4 + r);
      const int s = qw + qt * 16 + lg * 4 + r;
#pragma unroll
      for (int dt = 0; dt < 4; ++dt)
        attn[((size_t)(b * SEQ + s)) * DMODEL + h * DH + dt * 16 + l15] =
            f2bf(O[qt][dt][r] * iv);
    }
  }
}

// ---------------------------------------------------------------------------
extern "C" void kernel_launch(void* const* d_in, const int* in_sizes, int n_in,
                              void* d_out, int out_size, void* d_ws, size_t ws_size,
                              hipStream_t stream) {
  const float* x  = (const float*)d_in[0];
  // d_in[1] = causal mask (tril) — structure known, not read
  const float* Wq = (const float*)d_in[2];
  const float* Wk = (const float*)d_in[3];
  const float* Wv = (const float*)d_in[4];
  const float* Wo = (const float*)d_in[5];
  float* out = (float*)d_out;

  unsigned short* ws = (unsigned short*)d_ws;
  const size_t MEL = (size_t)1024 * 1024;
  unsigned short* xb   = ws;            // 4M elems
  unsigned short* wqkv = xb + 4 * MEL;  // 3M (Wq|Wk|Wv rows)
  unsigned short* wo   = wqkv + 3 * MEL;// 1M
  unsigned short* qb   = wo + MEL;      // 4M  [bh][s][64]
  unsigned short* kb   = qb + 4 * MEL;  // 4M  [bh][s][64]
  unsigned short* vtb  = kb + 4 * MEL;  // 4M  [bh][64][s]
  unsigned short* attn = vtb + 4 * MEL; // 4M  [b*s][1024]

  cvt8<<<2048, 256, 0, stream>>>(x, xb, 524288);
  cvt8<<<512, 256, 0, stream>>>(Wq, wqkv, 131072);
  cvt8<<<512, 256, 0, stream>>>(Wk, wqkv + MEL, 131072);
  cvt8<<<512, 256, 0, stream>>>(Wv, wqkv + 2 * MEL, 131072);
  cvt8<<<512, 256, 0, stream>>>(Wo, wo, 131072);

  dim3 g1(3072 / 128, 4096 / 128);  // QKV projection
  gemm_bt<0><<<g1, 256, 0, stream>>>(xb, wqkv, DMODEL, qb, kb, vtb, nullptr);

  dim3 g2(16, BATCH * HEADS);  // attention: 128 q rows per block
  attn_fwd<<<g2, 256, 0, stream>>>(qb, kb, vtb, attn);

  dim3 g3(1024 / 128, 4096 / 128);  // output projection
  gemm_bt<1><<<g3, 256, 0, stream>>>(attn, wo, DMODEL, nullptr, nullptr, nullptr, out);
}

// Round 3
// 189.498 us; speedup vs baseline: 1.1533x; 1.1020x over previous
//
#include <hip/hip_runtime.h>

typedef __bf16 bf16x8 __attribute__((ext_vector_type(8)));
typedef float f32x4 __attribute__((ext_vector_type(4)));
typedef unsigned short ushort8 __attribute__((ext_vector_type(8)));

#define DMODEL 1024
#define HEADS 16
#define DH 64
#define BATCH 2
#define SEQ 2048

__device__ __forceinline__ unsigned short f2bf(float f) {
  unsigned int u = __builtin_bit_cast(unsigned int, f);
  u += 0x7FFFu + ((u >> 16) & 1u);
  return (unsigned short)(u >> 16);
}

// ---------------- fp32 -> bf16 conversion (8 elems/thread) ----------------
__global__ void cvt8(const float* __restrict__ src, unsigned short* __restrict__ dst, int n8) {
  int i = blockIdx.x * 256 + threadIdx.x;
  if (i >= n8) return;
  const float4* s4 = (const float4*)src;
  float4 a = s4[(size_t)i * 2];
  float4 b = s4[(size_t)i * 2 + 1];
  ushort8 o;
  o[0] = f2bf(a.x); o[1] = f2bf(a.y); o[2] = f2bf(a.z); o[3] = f2bf(a.w);
  o[4] = f2bf(b.x); o[5] = f2bf(b.y); o[6] = f2bf(b.z); o[7] = f2bf(b.w);
  *(ushort8*)(dst + (size_t)i * 8) = o;
}

// ---------------- GEMM: C[M,N] = A[M,K] @ B[N,K]^T (bf16 in, f32 acc) -----
template<int MODE>
__global__ __launch_bounds__(256) void gemm_bt(
    const unsigned short* __restrict__ A, const unsigned short* __restrict__ Bm,
    int K,
    unsigned short* __restrict__ qb, unsigned short* __restrict__ kb,
    unsigned short* __restrict__ vt, float* __restrict__ fout)
{
  __shared__ alignas(16) unsigned short sA[128 * 32];
  __shared__ alignas(16) unsigned short sB[128 * 32];
  const int tid = threadIdx.x;
  const int lane = tid & 63, wave = tid >> 6;
  const int wm = wave >> 1, wn = wave & 1;
  const int l15 = lane & 15, lg = lane >> 4;
  const int row0 = blockIdx.y * 128, col0 = blockIdx.x * 128;

  f32x4 acc[4][4] = {};

  for (int k0 = 0; k0 < K; k0 += 32) {
#pragma unroll
    for (int i = 0; i < 2; ++i) {
      int flat = i * 256 + tid;
      int r = flat >> 2, cs = (flat & 3) * 8;
      __builtin_amdgcn_global_load_lds(
          (const __attribute__((address_space(1))) void*)(A + (size_t)(row0 + r) * K + k0 + cs),
          (__attribute__((address_space(3))) void*)(sA + flat * 8), 16, 0, 0);
      __builtin_amdgcn_global_load_lds(
          (const __attribute__((address_space(1))) void*)(Bm + (size_t)(col0 + r) * K + k0 + cs),
          (__attribute__((address_space(3))) void*)(sB + flat * 8), 16, 0, 0);
    }
    __syncthreads();
    bf16x8 af[4], bfr[4];
#pragma unroll
    for (int m = 0; m < 4; ++m)
      af[m] = *(const bf16x8*)&sA[(wm * 64 + m * 16 + l15) * 32 + lg * 8];
#pragma unroll
    for (int n = 0; n < 4; ++n)
      bfr[n] = *(const bf16x8*)&sB[(wn * 64 + n * 16 + l15) * 32 + lg * 8];
#pragma unroll
    for (int m = 0; m < 4; ++m)
#pragma unroll
      for (int n = 0; n < 4; ++n)
        acc[m][n] = __builtin_amdgcn_mfma_f32_16x16x32_bf16(af[m], bfr[n], acc[m][n], 0, 0, 0);
    __syncthreads();
  }

  // epilogue. C/D layout: col = lane&15, row = (lane>>4)*4 + reg  [m89]
#pragma unroll
  for (int m = 0; m < 4; ++m) {
#pragma unroll
    for (int n = 0; n < 4; ++n) {
      const int c = col0 + wn * 64 + n * 16 + l15;
#pragma unroll
      for (int reg = 0; reg < 4; ++reg) {
        const int r = row0 + wm * 64 + m * 16 + lg * 4 + reg;
        float v = acc[m][n][reg];
        if (MODE == 0) {
          const int which = c >> 10, c2 = c & 1023;
          const int h = c2 >> 6, d = c2 & 63;
          const int b = r >> 11, s = r & 2047;
          const unsigned short bv = f2bf(v);
          if (which == 0)
            qb[(((size_t)(b * HEADS + h)) * SEQ + s) * DH + d] = bv;
          else if (which == 1)
            kb[(((size_t)(b * HEADS + h)) * SEQ + s) * DH + d] = bv;
          else
            vt[(((size_t)(b * HEADS + h)) * DH + d) * SEQ + s] = bv;
        } else {
          fout[(size_t)r * DMODEL + c] = v;
        }
      }
    }
  }
}

// ---------------- causal flash attention ------------------------------------
// grid: (32, B*H), 256 threads = 4 waves. Block owns 64 q rows
// (q0 = (31-bx)*64, long blocks dispatched first). Wave owns 16 q rows.
// KVBLK = 64, double-buffered K and V^T tiles in LDS, staged via
// global_load_lds with PRE-SWIZZLED global source (chunk ^= row&7) so the
// swizzled ds_read_b128 fragment reads are bank-conflict-free.
// Swapped QK^T: st = mfma(K, Q) -> S^T, lane owns q = lane&15.
// LDS = 16+16+8 = 40KB -> 4 blocks/CU -> 16 waves/CU.
__global__ __launch_bounds__(256) void attn_fwd(
    const unsigned short* __restrict__ q, const unsigned short* __restrict__ k,
    const unsigned short* __restrict__ vt, unsigned short* __restrict__ attn)
{
  __shared__ alignas(16) unsigned short sK[2][64 * 64];  // [kv][d], swizzled
  __shared__ alignas(16) unsigned short sV[2][64 * 64];  // [d][kv], swizzled
  __shared__ alignas(16) unsigned short sP[4][16 * 64];  // per-wave, XOR (q&7)<<4

  const int tid = threadIdx.x, lane = tid & 63, wave = tid >> 6;
  const int l15 = lane & 15, lg = lane >> 4;
  const int bh = blockIdx.y;
  const int q0 = ((int)gridDim.x - 1 - (int)blockIdx.x) * 64;
  const int qw = q0 + wave * 16;

  const unsigned short* qg = q + ((size_t)bh * SEQ) * DH;
  const unsigned short* kg = k + ((size_t)bh * SEQ) * DH;
  const unsigned short* vg = vt + ((size_t)bh * DH) * SEQ;

  // Q fragments in registers: qf[ks], q = qw+l15, d = ks*32+lg*8
  bf16x8 qf[2];
#pragma unroll
  for (int ks = 0; ks < 2; ++ks)
    qf[ks] = *(const bf16x8*)(qg + (size_t)(qw + l15) * DH + ks * 32 + lg * 8);

  f32x4 O[4] = {};
  float m_r = -1e30f, l_r = 0.f;

  const int nt = q0 / 64 + 1;

  auto stage = [&](int bi, int kv0) {
#pragma unroll
    for (int ph = 0; ph < 2; ++ph) {
      const int flat = ph * 256 + tid;
      const int row = flat >> 3;
      const int c = (flat & 7) ^ (row & 7);
      __builtin_amdgcn_global_load_lds(
          (const __attribute__((address_space(1))) void*)(kg + (size_t)(kv0 + row) * DH + c * 8),
          (__attribute__((address_space(3))) void*)(&sK[bi][flat * 8]), 16, 0, 0);
      __builtin_amdgcn_global_load_lds(
          (const __attribute__((address_space(1))) void*)(vg + (size_t)row * SEQ + kv0 + c * 8),
          (__attribute__((address_space(3))) void*)(&sV[bi][flat * 8]), 16, 0, 0);
    }
  };

  stage(0, 0);
  __syncthreads();

  const float CSC = 0.18033688011112042f;  // 0.125 * log2(e)
  const float THR = 44.3614195558365f;     // 8 / CSC

  for (int t = 0; t < nt; ++t) {
    const int cur = t & 1;
    const int kv0 = t * 64;
    if (t + 1 < nt) stage(cur ^ 1, kv0 + 64);

    if (kv0 <= qw + 15) {
      // ---- QK^T: st[kt], rows kv = kv0+kt*16+lg*4+r, col q = qw+l15
      f32x4 st[4] = {};
      const char* sKb = (const char*)&sK[cur][0];
      __builtin_amdgcn_s_setprio(1);
#pragma unroll
      for (int kt = 0; kt < 4; ++kt) {
        const int row = kt * 16 + l15;
        const bf16x8 kf0 = *(const bf16x8*)(sKb + row * 128 + ((lg ^ (row & 7)) * 16));
        const bf16x8 kf1 = *(const bf16x8*)(sKb + row * 128 + (((4 + lg) ^ (row & 7)) * 16));
        st[kt] = __builtin_amdgcn_mfma_f32_16x16x32_bf16(kf0, qf[0], st[kt], 0, 0, 0);
        st[kt] = __builtin_amdgcn_mfma_f32_16x16x32_bf16(kf1, qf[1], st[kt], 0, 0, 0);
      }
      __builtin_amdgcn_s_setprio(0);

      // ---- mask + max
      const bool needmask = (kv0 + 63 > qw);
      float mx = -1e30f;
#pragma unroll
      for (int kt = 0; kt < 4; ++kt)
#pragma unroll
        for (int r = 0; r < 4; ++r) {
          float v = st[kt][r];
          if (needmask) {
            const int kv = kv0 + kt * 16 + lg * 4 + r;
            const int qgl = qw + l15;
            v = (kv <= qgl) ? v : -1e30f;
            st[kt][r] = v;
          }
          mx = fmaxf(mx, v);
        }
      mx = fmaxf(mx, __shfl_xor(mx, 16));
      mx = fmaxf(mx, __shfl_xor(mx, 32));

      // ---- defer-max (T13): rescale only when max grew past threshold
      if (!__all(mx - m_r <= THR)) {
        const float mn = fmaxf(m_r, mx);
        const float al = exp2f((m_r - mn) * CSC);
        l_r *= al;
        m_r = mn;
#pragma unroll
        for (int r = 0; r < 4; ++r) {
          const float ab = __shfl(al, lg * 4 + r);
#pragma unroll
          for (int dt = 0; dt < 4; ++dt) O[dt][r] *= ab;
        }
      }

      // ---- exp, row-sum, pack P -> per-wave swizzled LDS
      unsigned short* sPw = &sP[wave][0];
      float ps = 0.f;
#pragma unroll
      for (int kt = 0; kt < 4; ++kt) {
        float e0 = exp2f((st[kt][0] - m_r) * CSC);
        float e1 = exp2f((st[kt][1] - m_r) * CSC);
        float e2 = exp2f((st[kt][2] - m_r) * CSC);
        float e3 = exp2f((st[kt][3] - m_r) * CSC);
        ps += (e0 + e1) + (e2 + e3);
        uint2 w;
        w.x = (unsigned)f2bf(e0) | ((unsigned)f2bf(e1) << 16);
        w.y = (unsigned)f2bf(e2) | ((unsigned)f2bf(e3) << 16);
        const int byteoff = (l15 * 128 + kt * 32 + lg * 8) ^ ((l15 & 7) << 4);
        *(uint2*)((char*)sPw + byteoff) = w;
      }
      ps += __shfl_xor(ps, 16);
      ps += __shfl_xor(ps, 32);
      l_r += ps;

      asm volatile("s_waitcnt lgkmcnt(0)" ::: "memory");
      __builtin_amdgcn_sched_barrier(0);

      // ---- PV: O[dt] += P[q][kv] * V^T[d][kv]
      const char* sVb = (const char*)&sV[cur][0];
      __builtin_amdgcn_s_setprio(1);
#pragma unroll
      for (int ks = 0; ks < 2; ++ks) {
        const bf16x8 pf = *(const bf16x8*)((const char*)sPw +
            ((l15 * 128 + ks * 64 + lg * 16) ^ ((l15 & 7) << 4)));
#pragma unroll
        for (int dt = 0; dt < 4; ++dt) {
          const int row = dt * 16 + l15;
          const bf16x8 vf = *(const bf16x8*)(sVb + row * 128 + (((ks * 4 + lg) ^ (row & 7)) * 16));
          O[dt] = __builtin_amdgcn_mfma_f32_16x16x32_bf16(pf, vf, O[dt], 0, 0, 0);
        }
      }
      __builtin_amdgcn_s_setprio(0);
    }
    __syncthreads();
  }

  // ---- epilogue: divide by l, write bf16 attn_out [b, s, h*64+d]
  const int b = bh >> 4, h = bh & 15;
  const float inv = 1.0f / l_r;
#pragma unroll
  for (int r = 0; r < 4; ++r) {
    const float iv = __shfl(inv, lg * 4 + r);
    const int s = qw + lg * 4 + r;
#pragma unroll
    for (int dt = 0; dt < 4; ++dt)
      attn[((size_t)(b * SEQ + s)) * DMODEL + h * DH + dt * 16 + l15] =
          f2bf(O[dt][r] * iv);
  }
}

// ---------------------------------------------------------------------------
extern "C" void kernel_launch(void* const* d_in, const int* in_sizes, int n_in,
                              void* d_out, int out_size, void* d_ws, size_t ws_size,
                              hipStream_t stream) {
  const float* x  = (const float*)d_in[0];
  // d_in[1] = causal mask (tril) — structure known, not read
  const float* Wq = (const float*)d_in[2];
  const float* Wk = (const float*)d_in[3];
  const float* Wv = (const float*)d_in[4];
  const float* Wo = (const float*)d_in[5];
  float* out = (float*)d_out;

  unsigned short* ws = (unsigned short*)d_ws;
  const size_t MEL = (size_t)1024 * 1024;
  unsigned short* xb   = ws;            // 4M elems
  unsigned short* wqkv = xb + 4 * MEL;  // 3M (Wq|Wk|Wv rows)
  unsigned short* wo   = wqkv + 3 * MEL;// 1M
  unsigned short* qb   = wo + MEL;      // 4M  [bh][s][64]
  unsigned short* kb   = qb + 4 * MEL;  // 4M  [bh][s][64]
  unsigned short* vtb  = kb + 4 * MEL;  // 4M  [bh][64][s]
  unsigned short* attn = vtb + 4 * MEL; // 4M  [b*s][1024]

  cvt8<<<2048, 256, 0, stream>>>(x, xb, 524288);
  cvt8<<<512, 256, 0, stream>>>(Wq, wqkv, 131072);
  cvt8<<<512, 256, 0, stream>>>(Wk, wqkv + MEL, 131072);
  cvt8<<<512, 256, 0, stream>>>(Wv, wqkv + 2 * MEL, 131072);
  cvt8<<<512, 256, 0, stream>>>(Wo, wo, 131072);

  dim3 g1(3072 / 128, 4096 / 128);  // QKV projection
  gemm_bt<0><<<g1, 256, 0, stream>>>(xb, wqkv, DMODEL, qb, kb, vtb, nullptr);

  dim3 g2(32, BATCH * HEADS);  // attention: 64 q rows per block
  attn_fwd<<<g2, 256, 0, stream>>>(qb, kb, vtb, attn);

  dim3 g3(1024 / 128, 4096 / 128);  // output projection
  gemm_bt<1><<<g3, 256, 0, stream>>>(attn, wo, DMODEL, nullptr, nullptr, nullptr, out);
}

// Round 4
// 156.345 us; speedup vs baseline: 1.3978x; 1.2120x over previous
//
#include <hip/hip_runtime.h>

typedef __bf16 bf16x8 __attribute__((ext_vector_type(8)));
typedef float f32x4 __attribute__((ext_vector_type(4)));
typedef unsigned short ushort8 __attribute__((ext_vector_type(8)));

#define DMODEL 1024
#define HEADS 16
#define DH 64
#define BATCH 2
#define SEQ 2048

__device__ __forceinline__ unsigned short f2bf(float f) {
  unsigned int u = __builtin_bit_cast(unsigned int, f);
  u += 0x7FFFu + ((u >> 16) & 1u);
  return (unsigned short)(u >> 16);
}

// ---------------- fp32 -> bf16 conversion (8 elems/thread) ----------------
__global__ void cvt8(const float* __restrict__ src, unsigned short* __restrict__ dst, int n8) {
  int i = blockIdx.x * 256 + threadIdx.x;
  if (i >= n8) return;
  const float4* s4 = (const float4*)src;
  float4 a = s4[(size_t)i * 2];
  float4 b = s4[(size_t)i * 2 + 1];
  ushort8 o;
  o[0] = f2bf(a.x); o[1] = f2bf(a.y); o[2] = f2bf(a.z); o[3] = f2bf(a.w);
  o[4] = f2bf(b.x); o[5] = f2bf(b.y); o[6] = f2bf(b.z); o[7] = f2bf(b.w);
  *(ushort8*)(dst + (size_t)i * 8) = o;
}

// ---------------- GEMM: C[M,N] = A[M,K] @ B[N,K]^T (bf16 in, f32 acc) -----
template<int MODE>
__global__ __launch_bounds__(256) void gemm_bt(
    const unsigned short* __restrict__ A, const unsigned short* __restrict__ Bm,
    int K,
    unsigned short* __restrict__ qb, unsigned short* __restrict__ kb,
    unsigned short* __restrict__ vt, float* __restrict__ fout)
{
  __shared__ alignas(16) unsigned short sA[128 * 32];
  __shared__ alignas(16) unsigned short sB[128 * 32];
  const int tid = threadIdx.x;
  const int lane = tid & 63, wave = tid >> 6;
  const int wm = wave >> 1, wn = wave & 1;
  const int l15 = lane & 15, lg = lane >> 4;
  const int row0 = blockIdx.y * 128, col0 = blockIdx.x * 128;

  f32x4 acc[4][4] = {};

  for (int k0 = 0; k0 < K; k0 += 32) {
#pragma unroll
    for (int i = 0; i < 2; ++i) {
      int flat = i * 256 + tid;
      int r = flat >> 2, cs = (flat & 3) * 8;
      __builtin_amdgcn_global_load_lds(
          (const __attribute__((address_space(1))) void*)(A + (size_t)(row0 + r) * K + k0 + cs),
          (__attribute__((address_space(3))) void*)(sA + flat * 8), 16, 0, 0);
      __builtin_amdgcn_global_load_lds(
          (const __attribute__((address_space(1))) void*)(Bm + (size_t)(col0 + r) * K + k0 + cs),
          (__attribute__((address_space(3))) void*)(sB + flat * 8), 16, 0, 0);
    }
    __syncthreads();
    bf16x8 af[4], bfr[4];
#pragma unroll
    for (int m = 0; m < 4; ++m)
      af[m] = *(const bf16x8*)&sA[(wm * 64 + m * 16 + l15) * 32 + lg * 8];
#pragma unroll
    for (int n = 0; n < 4; ++n)
      bfr[n] = *(const bf16x8*)&sB[(wn * 64 + n * 16 + l15) * 32 + lg * 8];
#pragma unroll
    for (int m = 0; m < 4; ++m)
#pragma unroll
      for (int n = 0; n < 4; ++n)
        acc[m][n] = __builtin_amdgcn_mfma_f32_16x16x32_bf16(af[m], bfr[n], acc[m][n], 0, 0, 0);
    __syncthreads();
  }

  // epilogue. C/D layout: col = lane&15, row = (lane>>4)*4 + reg  [m89]
#pragma unroll
  for (int m = 0; m < 4; ++m) {
#pragma unroll
    for (int n = 0; n < 4; ++n) {
      const int c = col0 + wn * 64 + n * 16 + l15;
#pragma unroll
      for (int reg = 0; reg < 4; ++reg) {
        const int r = row0 + wm * 64 + m * 16 + lg * 4 + reg;
        float v = acc[m][n][reg];
        if (MODE == 0) {
          const int which = c >> 10, c2 = c & 1023;
          const int h = c2 >> 6, d = c2 & 63;
          const int b = r >> 11, s = r & 2047;
          const unsigned short bv = f2bf(v);
          if (which == 0)
            qb[(((size_t)(b * HEADS + h)) * SEQ + s) * DH + d] = bv;
          else if (which == 1)
            kb[(((size_t)(b * HEADS + h)) * SEQ + s) * DH + d] = bv;
          else
            vt[(((size_t)(b * HEADS + h)) * DH + d) * SEQ + s] = bv;
        } else {
          fout[(size_t)r * DMODEL + c] = v;
        }
      }
    }
  }
}

// ---------------- causal flash attention (paired q-tiles) ------------------
// grid: (16, B*H), 256 threads = 4 waves. Block j sequentially processes
// q-tile A (q0 = j*64, j+1 kv-tiles) and q-tile B (q0 = (31-j)*64, 32-j
// kv-tiles) -> exactly 33 kv-tile iterations for EVERY block (uniform load).
// KVBLK = 64, double-buffered K/V^T in LDS, staged via global_load_lds with
// pre-swizzled global source. Swapped QK^T; per-wave swizzled P buffer.
__global__ __launch_bounds__(256) void attn_fwd(
    const unsigned short* __restrict__ q, const unsigned short* __restrict__ k,
    const unsigned short* __restrict__ vt, unsigned short* __restrict__ attn)
{
  __shared__ alignas(16) unsigned short sK[2][64 * 64];  // [kv][d], swizzled
  __shared__ alignas(16) unsigned short sV[2][64 * 64];  // [d][kv], swizzled
  __shared__ alignas(16) unsigned short sP[4][16 * 64];  // per-wave, XOR (q&7)<<4

  const int tid = threadIdx.x, lane = tid & 63, wave = tid >> 6;
  const int l15 = lane & 15, lg = lane >> 4;
  const int bh = blockIdx.y;
  const int j = blockIdx.x;
  const int q0a = j * 64, q0b = (31 - j) * 64;
  const int ntA = j + 1, ntB = 32 - j, ntot = 33;

  const unsigned short* qg = q + ((size_t)bh * SEQ) * DH;
  const unsigned short* kg = k + ((size_t)bh * SEQ) * DH;
  const unsigned short* vg = vt + ((size_t)bh * DH) * SEQ;

  // Q fragments for both phases: q row = q0 + wave*16 + l15, d = ks*32+lg*8
  bf16x8 qfA[2], qfB[2];
#pragma unroll
  for (int ks = 0; ks < 2; ++ks) {
    qfA[ks] = *(const bf16x8*)(qg + (size_t)(q0a + wave * 16 + l15) * DH + ks * 32 + lg * 8);
    qfB[ks] = *(const bf16x8*)(qg + (size_t)(q0b + wave * 16 + l15) * DH + ks * 32 + lg * 8);
  }

  f32x4 O[4] = {};
  float m_r = -1e30f, l_r = 0.f;

  // thread-constant staging offsets (swizzled source chunks)
  const int f0 = tid, f1 = 256 + tid;
  const int r0 = f0 >> 3, r1 = f1 >> 3;
  const int c0 = (f0 & 7) ^ (r0 & 7), c1 = (f1 & 7) ^ (r1 & 7);
  const int kOff0 = r0 * DH + c0 * 8, kOff1 = r1 * DH + c1 * 8;
  const int vOff0 = r0 * SEQ + c0 * 8, vOff1 = r1 * SEQ + c1 * 8;

  auto stage = [&](int bi, int kv0) {
    __builtin_amdgcn_global_load_lds(
        (const __attribute__((address_space(1))) void*)(kg + (size_t)kv0 * DH + kOff0),
        (__attribute__((address_space(3))) void*)(&sK[bi][f0 * 8]), 16, 0, 0);
    __builtin_amdgcn_global_load_lds(
        (const __attribute__((address_space(1))) void*)(kg + (size_t)kv0 * DH + kOff1),
        (__attribute__((address_space(3))) void*)(&sK[bi][f1 * 8]), 16, 0, 0);
    __builtin_amdgcn_global_load_lds(
        (const __attribute__((address_space(1))) void*)(vg + (size_t)kv0 + vOff0),
        (__attribute__((address_space(3))) void*)(&sV[bi][f0 * 8]), 16, 0, 0);
    __builtin_amdgcn_global_load_lds(
        (const __attribute__((address_space(1))) void*)(vg + (size_t)kv0 + vOff1),
        (__attribute__((address_space(3))) void*)(&sV[bi][f1 * 8]), 16, 0, 0);
  };

  const float CSC = 0.18033688011112042f;  // 0.125 * log2(e)
  const float THR = 44.3614195558365f;     // 8 / CSC

  // one kv-tile step (shared by both phases)
  auto tile = [&](const bf16x8 (&qf)[2], int kv0, int cur, int qwv) {
    // ---- QK^T: st[kt], rows kv = kv0+kt*16+lg*4+r, col q = qwv+l15
    f32x4 st[4] = {};
    const char* sKb = (const char*)&sK[cur][0];
    __builtin_amdgcn_s_setprio(1);
#pragma unroll
    for (int kt = 0; kt < 4; ++kt) {
      const int row = kt * 16 + l15;
      const bf16x8 kf0 = *(const bf16x8*)(sKb + row * 128 + ((lg ^ (row & 7)) * 16));
      const bf16x8 kf1 = *(const bf16x8*)(sKb + row * 128 + (((4 + lg) ^ (row & 7)) * 16));
      st[kt] = __builtin_amdgcn_mfma_f32_16x16x32_bf16(kf0, qf[0], st[kt], 0, 0, 0);
      st[kt] = __builtin_amdgcn_mfma_f32_16x16x32_bf16(kf1, qf[1], st[kt], 0, 0, 0);
    }
    __builtin_amdgcn_s_setprio(0);

    // ---- mask + max
    const bool needmask = (kv0 + 63 > qwv);
    const int qgl = qwv + l15;
    float mx = -1e30f;
#pragma unroll
    for (int kt = 0; kt < 4; ++kt)
#pragma unroll
      for (int r = 0; r < 4; ++r) {
        float v = st[kt][r];
        if (needmask) {
          const int kv = kv0 + kt * 16 + lg * 4 + r;
          v = (kv <= qgl) ? v : -1e30f;
          st[kt][r] = v;
        }
        mx = fmaxf(mx, v);
      }
    mx = fmaxf(mx, __shfl_xor(mx, 16));
    mx = fmaxf(mx, __shfl_xor(mx, 32));

    // ---- defer-max (T13)
    if (!__all(mx - m_r <= THR)) {
      const float mn = fmaxf(m_r, mx);
      const float al = exp2f((m_r - mn) * CSC);
      l_r *= al;
      m_r = mn;
#pragma unroll
      for (int r = 0; r < 4; ++r) {
        const float ab = __shfl(al, lg * 4 + r);
#pragma unroll
        for (int dt = 0; dt < 4; ++dt) O[dt][r] *= ab;
      }
    }

    // ---- exp (fma-folded), row-sum, pack P via v_cvt_pk_bf16_f32
    unsigned short* sPw = &sP[wave][0];
    const float nm = -m_r * CSC;
    float ps = 0.f;
#pragma unroll
    for (int kt = 0; kt < 4; ++kt) {
      const float e0 = exp2f(__builtin_fmaf(st[kt][0], CSC, nm));
      const float e1 = exp2f(__builtin_fmaf(st[kt][1], CSC, nm));
      const float e2 = exp2f(__builtin_fmaf(st[kt][2], CSC, nm));
      const float e3 = exp2f(__builtin_fmaf(st[kt][3], CSC, nm));
      ps += (e0 + e1) + (e2 + e3);
      unsigned w0, w1;
      asm("v_cvt_pk_bf16_f32 %0, %1, %2" : "=v"(w0) : "v"(e0), "v"(e1));
      asm("v_cvt_pk_bf16_f32 %0, %1, %2" : "=v"(w1) : "v"(e2), "v"(e3));
      uint2 w; w.x = w0; w.y = w1;
      const int byteoff = l15 * 128 + ((kt * 32 + lg * 8) ^ ((l15 & 7) << 4));
      *(uint2*)((char*)sPw + byteoff) = w;
    }
    ps += __shfl_xor(ps, 16);
    ps += __shfl_xor(ps, 32);
    l_r += ps;

    asm volatile("s_waitcnt lgkmcnt(0)" ::: "memory");
    __builtin_amdgcn_sched_barrier(0);

    // ---- PV: O[dt] += P[q][kv] * V^T[d][kv]
    const char* sVb = (const char*)&sV[cur][0];
    __builtin_amdgcn_s_setprio(1);
#pragma unroll
    for (int ks = 0; ks < 2; ++ks) {
      const bf16x8 pf = *(const bf16x8*)((const char*)sPw +
          (l15 * 128 + ((ks * 64 + lg * 16) ^ ((l15 & 7) << 4))));
#pragma unroll
      for (int dt = 0; dt < 4; ++dt) {
        const int row = dt * 16 + l15;
        const bf16x8 vf = *(const bf16x8*)(sVb + row * 128 + (((ks * 4 + lg) ^ (row & 7)) * 16));
        O[dt] = __builtin_amdgcn_mfma_f32_16x16x32_bf16(pf, vf, O[dt], 0, 0, 0);
      }
    }
    __builtin_amdgcn_s_setprio(0);
  };

  const int b = bh >> 4, h = bh & 15;
  auto writeOut = [&](int q0w) {
    const float inv = 1.0f / l_r;
#pragma unroll
    for (int r = 0; r < 4; ++r) {
      const float iv = __shfl(inv, lg * 4 + r);
      const int s = q0w + wave * 16 + lg * 4 + r;
#pragma unroll
      for (int dt = 0; dt < 4; ++dt)
        attn[((size_t)(b * SEQ + s)) * DMODEL + h * DH + dt * 16 + l15] =
            f2bf(O[dt][r] * iv);
    }
  };

  stage(0, 0);
  __syncthreads();

  int u = 0;
  // ---- phase A: q-tile j, kv tiles 0..ntA-1
  for (int t = 0; t < ntA; ++t, ++u) {
    const int cur = u & 1;
    if (u + 1 < ntot) {
      const int un = u + 1;
      stage(cur ^ 1, (un < ntA ? un : un - ntA) * 64);
    }
    tile(qfA, t * 64, cur, q0a + wave * 16);
    __syncthreads();
  }
  writeOut(q0a);
#pragma unroll
  for (int dt = 0; dt < 4; ++dt) O[dt] = f32x4{0.f, 0.f, 0.f, 0.f};
  m_r = -1e30f; l_r = 0.f;

  // ---- phase B: q-tile 31-j, kv tiles 0..ntB-1
  for (int t = 0; t < ntB; ++t, ++u) {
    const int cur = u & 1;
    if (u + 1 < ntot) stage(cur ^ 1, (t + 1) * 64);
    tile(qfB, t * 64, cur, q0b + wave * 16);
    __syncthreads();
  }
  writeOut(q0b);
}

// ---------------------------------------------------------------------------
extern "C" void kernel_launch(void* const* d_in, const int* in_sizes, int n_in,
                              void* d_out, int out_size, void* d_ws, size_t ws_size,
                              hipStream_t stream) {
  const float* x  = (const float*)d_in[0];
  // d_in[1] = causal mask (tril) — structure known, not read
  const float* Wq = (const float*)d_in[2];
  const float* Wk = (const float*)d_in[3];
  const float* Wv = (const float*)d_in[4];
  const float* Wo = (const float*)d_in[5];
  float* out = (float*)d_out;

  unsigned short* ws = (unsigned short*)d_ws;
  const size_t MEL = (size_t)1024 * 1024;
  unsigned short* xb   = ws;            // 4M elems
  unsigned short* wqkv = xb + 4 * MEL;  // 3M (Wq|Wk|Wv rows)
  unsigned short* wo   = wqkv + 3 * MEL;// 1M
  unsigned short* qb   = wo + MEL;      // 4M  [bh][s][64]
  unsigned short* kb   = qb + 4 * MEL;  // 4M  [bh][s][64]
  unsigned short* vtb  = kb + 4 * MEL;  // 4M  [bh][64][s]
  unsigned short* attn = vtb + 4 * MEL; // 4M  [b*s][1024]

  cvt8<<<2048, 256, 0, stream>>>(x, xb, 524288);
  cvt8<<<512, 256, 0, stream>>>(Wq, wqkv, 131072);
  cvt8<<<512, 256, 0, stream>>>(Wk, wqkv + MEL, 131072);
  cvt8<<<512, 256, 0, stream>>>(Wv, wqkv + 2 * MEL, 131072);
  cvt8<<<512, 256, 0, stream>>>(Wo, wo, 131072);

  dim3 g1(3072 / 128, 4096 / 128);  // QKV projection
  gemm_bt<0><<<g1, 256, 0, stream>>>(xb, wqkv, DMODEL, qb, kb, vtb, nullptr);

  dim3 g2(16, BATCH * HEADS);  // attention: paired q-tiles, uniform 33 iters
  attn_fwd<<<g2, 256, 0, stream>>>(qb, kb, vtb, attn);

  dim3 g3(1024 / 128, 4096 / 128);  // output projection
  gemm_bt<1><<<g3, 256, 0, stream>>>(attn, wo, DMODEL, nullptr, nullptr, nullptr, out);
}

// Round 5
// 144.733 us; speedup vs baseline: 1.5100x; 1.0802x over previous
//
#include <hip/hip_runtime.h>

typedef __bf16 bf16x8 __attribute__((ext_vector_type(8)));
typedef float f32x4 __attribute__((ext_vector_type(4)));
typedef unsigned short ushort8 __attribute__((ext_vector_type(8)));

#define DMODEL 1024
#define HEADS 16
#define DH 64
#define BATCH 2
#define SEQ 2048

__device__ __forceinline__ unsigned short f2bf(float f) {
  unsigned int u = __builtin_bit_cast(unsigned int, f);
  u += 0x7FFFu + ((u >> 16) & 1u);
  return (unsigned short)(u >> 16);
}

// ---------------- fp32 -> bf16 conversion (8 elems/thread) ----------------
__global__ void cvt8(const float* __restrict__ src, unsigned short* __restrict__ dst, int n8) {
  int i = blockIdx.x * 256 + threadIdx.x;
  if (i >= n8) return;
  const float4* s4 = (const float4*)src;
  float4 a = s4[(size_t)i * 2];
  float4 b = s4[(size_t)i * 2 + 1];
  ushort8 o;
  o[0] = f2bf(a.x); o[1] = f2bf(a.y); o[2] = f2bf(a.z); o[3] = f2bf(a.w);
  o[4] = f2bf(b.x); o[5] = f2bf(b.y); o[6] = f2bf(b.z); o[7] = f2bf(b.w);
  *(ushort8*)(dst + (size_t)i * 8) = o;
}

// ---------------- GEMM: C[M,N] = A[M,K] @ B[N,K]^T (bf16 in, f32 acc) -----
template<int MODE>
__global__ __launch_bounds__(256) void gemm_bt(
    const unsigned short* __restrict__ A, const unsigned short* __restrict__ Bm,
    int K,
    unsigned short* __restrict__ qb, unsigned short* __restrict__ kb,
    unsigned short* __restrict__ vt, float* __restrict__ fout)
{
  __shared__ alignas(16) unsigned short sA[128 * 32];
  __shared__ alignas(16) unsigned short sB[128 * 32];
  const int tid = threadIdx.x;
  const int lane = tid & 63, wave = tid >> 6;
  const int wm = wave >> 1, wn = wave & 1;
  const int l15 = lane & 15, lg = lane >> 4;
  const int row0 = blockIdx.y * 128, col0 = blockIdx.x * 128;

  f32x4 acc[4][4] = {};

  for (int k0 = 0; k0 < K; k0 += 32) {
#pragma unroll
    for (int i = 0; i < 2; ++i) {
      int flat = i * 256 + tid;
      int r = flat >> 2, cs = (flat & 3) * 8;
      __builtin_amdgcn_global_load_lds(
          (const __attribute__((address_space(1))) void*)(A + (size_t)(row0 + r) * K + k0 + cs),
          (__attribute__((address_space(3))) void*)(sA + flat * 8), 16, 0, 0);
      __builtin_amdgcn_global_load_lds(
          (const __attribute__((address_space(1))) void*)(Bm + (size_t)(col0 + r) * K + k0 + cs),
          (__attribute__((address_space(3))) void*)(sB + flat * 8), 16, 0, 0);
    }
    __syncthreads();
    bf16x8 af[4], bfr[4];
#pragma unroll
    for (int m = 0; m < 4; ++m)
      af[m] = *(const bf16x8*)&sA[(wm * 64 + m * 16 + l15) * 32 + lg * 8];
#pragma unroll
    for (int n = 0; n < 4; ++n)
      bfr[n] = *(const bf16x8*)&sB[(wn * 64 + n * 16 + l15) * 32 + lg * 8];
#pragma unroll
    for (int m = 0; m < 4; ++m)
#pragma unroll
      for (int n = 0; n < 4; ++n)
        acc[m][n] = __builtin_amdgcn_mfma_f32_16x16x32_bf16(af[m], bfr[n], acc[m][n], 0, 0, 0);
    __syncthreads();
  }

  // epilogue. C/D layout: col = lane&15, row = (lane>>4)*4 + reg  [m89]
#pragma unroll
  for (int m = 0; m < 4; ++m) {
#pragma unroll
    for (int n = 0; n < 4; ++n) {
      const int c = col0 + wn * 64 + n * 16 + l15;
#pragma unroll
      for (int reg = 0; reg < 4; ++reg) {
        const int r = row0 + wm * 64 + m * 16 + lg * 4 + reg;
        float v = acc[m][n][reg];
        if (MODE == 0) {
          const int which = c >> 10, c2 = c & 1023;
          const int h = c2 >> 6, d = c2 & 63;
          const int b = r >> 11, s = r & 2047;
          const unsigned short bv = f2bf(v);
          if (which == 0)
            qb[(((size_t)(b * HEADS + h)) * SEQ + s) * DH + d] = bv;
          else if (which == 1)
            kb[(((size_t)(b * HEADS + h)) * SEQ + s) * DH + d] = bv;
          else
            vt[(((size_t)(b * HEADS + h)) * DH + d) * SEQ + s] = bv;
        } else {
          fout[(size_t)r * DMODEL + c] = v;
        }
      }
    }
  }
}

// ---------------- causal flash attention (paired q-tiles + team kv-split) --
// grid: (16, B*H), 512 threads = 8 waves = 2 teams x 4 waves.
// Block j processes q-tile A (q0=j*64, ntA=j+1 kv-tiles) then q-tile B
// (q0=(31-j)*64, ntB=32-j) -> 33 kv-tiles total, uniform across blocks.
// Team 0 takes even kv-tiles, team 1 odd; each keeps partial (O,m,l);
// teams merge in LDS at each phase end (flash split-k combine).
// Single-buffered per-team K/V (48 KB LDS) -> 2 blocks/CU = 16 waves/CU.
__global__ __launch_bounds__(512, 4) void attn_fwd(
    const unsigned short* __restrict__ q, const unsigned short* __restrict__ k,
    const unsigned short* __restrict__ vt, unsigned short* __restrict__ attn)
{
  __shared__ alignas(16) unsigned short sK[2][64 * 64];  // [team][kv][d], swizzled
  __shared__ alignas(16) unsigned short sV[2][64 * 64];  // [team][d][kv], swizzled
  __shared__ alignas(16) unsigned short sP[8][16 * 64];  // per-wave, swizzled

  const int tid = threadIdx.x, lane = tid & 63, wave = tid >> 6;
  const int team = wave >> 2, wsub = wave & 3;
  const int l15 = lane & 15, lg = lane >> 4;
  const int bh = blockIdx.y;
  const int j = blockIdx.x;
  const int q0a = j * 64, q0b = (31 - j) * 64;
  const int ntA = j + 1, ntB = 32 - j;

  const unsigned short* qg = q + ((size_t)bh * SEQ) * DH;
  const unsigned short* kg = k + ((size_t)bh * SEQ) * DH;
  const unsigned short* vg = vt + ((size_t)bh * DH) * SEQ;

  // Q fragments: q row = q0 + wsub*16 + l15, d = ks*32 + lg*8
  bf16x8 qfA[2], qfB[2];
#pragma unroll
  for (int ks = 0; ks < 2; ++ks) {
    qfA[ks] = *(const bf16x8*)(qg + (size_t)(q0a + wsub * 16 + l15) * DH + ks * 32 + lg * 8);
    qfB[ks] = *(const bf16x8*)(qg + (size_t)(q0b + wsub * 16 + l15) * DH + ks * 32 + lg * 8);
  }

  f32x4 O[4] = {};
  float m_r = -1e30f, l_r = 0.f;

  // block-cooperative staging: all 512 threads stage 4 tiles (K0,V0,K1,V1)
  const int srow = tid >> 3;                 // 0..63
  const int sc = (tid & 7) ^ (srow & 7);     // swizzled source chunk
  const int kOff = srow * DH + sc * 8;
  const int vOff = srow * SEQ + sc * 8;

  auto stage = [&](int u0, int u1, int nt) {
    const int kv0 = u0 * 64;
    const int kv1 = (u1 < nt ? u1 : 0) * 64;
    __builtin_amdgcn_global_load_lds(
        (const __attribute__((address_space(1))) void*)(kg + (size_t)kv0 * DH + kOff),
        (__attribute__((address_space(3))) void*)(&sK[0][tid * 8]), 16, 0, 0);
    __builtin_amdgcn_global_load_lds(
        (const __attribute__((address_space(1))) void*)(vg + (size_t)kv0 + vOff),
        (__attribute__((address_space(3))) void*)(&sV[0][tid * 8]), 16, 0, 0);
    __builtin_amdgcn_global_load_lds(
        (const __attribute__((address_space(1))) void*)(kg + (size_t)kv1 * DH + kOff),
        (__attribute__((address_space(3))) void*)(&sK[1][tid * 8]), 16, 0, 0);
    __builtin_amdgcn_global_load_lds(
        (const __attribute__((address_space(1))) void*)(vg + (size_t)kv1 + vOff),
        (__attribute__((address_space(3))) void*)(&sV[1][tid * 8]), 16, 0, 0);
  };

  const float CSC = 0.18033688011112042f;  // 0.125 * log2(e)
  const float THR = 44.3614195558365f;     // 8 / CSC

  auto tile = [&](const bf16x8 (&qf)[2], int kv0, int qwv) {
    // ---- QK^T: st[kt], rows kv = kv0+kt*16+lg*4+r, col q = qwv+l15
    f32x4 st[4] = {};
    const char* sKb = (const char*)&sK[team][0];
    __builtin_amdgcn_s_setprio(1);
#pragma unroll
    for (int kt = 0; kt < 4; ++kt) {
      const int row = kt * 16 + l15;
      const bf16x8 kf0 = *(const bf16x8*)(sKb + row * 128 + ((lg ^ (row & 7)) * 16));
      const bf16x8 kf1 = *(const bf16x8*)(sKb + row * 128 + (((4 + lg) ^ (row & 7)) * 16));
      st[kt] = __builtin_amdgcn_mfma_f32_16x16x32_bf16(kf0, qf[0], st[kt], 0, 0, 0);
      st[kt] = __builtin_amdgcn_mfma_f32_16x16x32_bf16(kf1, qf[1], st[kt], 0, 0, 0);
    }
    __builtin_amdgcn_s_setprio(0);

    // ---- mask + max
    const bool needmask = (kv0 + 63 > qwv);
    const int qgl = qwv + l15;
    float mx = -1e30f;
#pragma unroll
    for (int kt = 0; kt < 4; ++kt)
#pragma unroll
      for (int r = 0; r < 4; ++r) {
        float v = st[kt][r];
        if (needmask) {
          const int kv = kv0 + kt * 16 + lg * 4 + r;
          v = (kv <= qgl) ? v : -1e30f;
          st[kt][r] = v;
        }
        mx = fmaxf(mx, v);
      }
    mx = fmaxf(mx, __shfl_xor(mx, 16));
    mx = fmaxf(mx, __shfl_xor(mx, 32));

    // ---- defer-max (T13)
    if (!__all(mx - m_r <= THR)) {
      const float mn = fmaxf(m_r, mx);
      const float al = exp2f((m_r - mn) * CSC);
      l_r *= al;
      m_r = mn;
#pragma unroll
      for (int r = 0; r < 4; ++r) {
        const float ab = __shfl(al, lg * 4 + r);
#pragma unroll
        for (int dt = 0; dt < 4; ++dt) O[dt][r] *= ab;
      }
    }

    // ---- exp (fma-folded), row-sum, pack P via v_cvt_pk_bf16_f32
    unsigned short* sPw = &sP[wave][0];
    const float nm = -m_r * CSC;
    float ps = 0.f;
#pragma unroll
    for (int kt = 0; kt < 4; ++kt) {
      const float e0 = exp2f(__builtin_fmaf(st[kt][0], CSC, nm));
      const float e1 = exp2f(__builtin_fmaf(st[kt][1], CSC, nm));
      const float e2 = exp2f(__builtin_fmaf(st[kt][2], CSC, nm));
      const float e3 = exp2f(__builtin_fmaf(st[kt][3], CSC, nm));
      ps += (e0 + e1) + (e2 + e3);
      unsigned w0, w1;
      asm("v_cvt_pk_bf16_f32 %0, %1, %2" : "=v"(w0) : "v"(e0), "v"(e1));
      asm("v_cvt_pk_bf16_f32 %0, %1, %2" : "=v"(w1) : "v"(e2), "v"(e3));
      uint2 w; w.x = w0; w.y = w1;
      const int byteoff = l15 * 128 + ((kt * 32 + lg * 8) ^ ((l15 & 7) << 4));
      *(uint2*)((char*)sPw + byteoff) = w;
    }
    ps += __shfl_xor(ps, 16);
    ps += __shfl_xor(ps, 32);
    l_r += ps;

    asm volatile("s_waitcnt lgkmcnt(0)" ::: "memory");
    __builtin_amdgcn_sched_barrier(0);

    // ---- PV: O[dt] += P[q][kv] * V^T[d][kv]
    const char* sVb = (const char*)&sV[team][0];
    __builtin_amdgcn_s_setprio(1);
#pragma unroll
    for (int ks = 0; ks < 2; ++ks) {
      const bf16x8 pf = *(const bf16x8*)((const char*)sPw +
          (l15 * 128 + ((ks * 64 + lg * 16) ^ ((l15 & 7) << 4))));
#pragma unroll
      for (int dt = 0; dt < 4; ++dt) {
        const int row = dt * 16 + l15;
        const bf16x8 vf = *(const bf16x8*)(sVb + row * 128 + (((ks * 4 + lg) ^ (row & 7)) * 16));
        O[dt] = __builtin_amdgcn_mfma_f32_16x16x32_bf16(pf, vf, O[dt], 0, 0, 0);
      }
    }
    __builtin_amdgcn_s_setprio(0);
  };

  const int b = bh >> 4, h = bh & 15;
  auto writeOut = [&](int q0w) {
    const float inv = 1.0f / l_r;
#pragma unroll
    for (int r = 0; r < 4; ++r) {
      const float iv = __shfl(inv, lg * 4 + r);
      const int s = q0w + wsub * 16 + lg * 4 + r;
#pragma unroll
      for (int dt = 0; dt < 4; ++dt)
        attn[((size_t)(b * SEQ + s)) * DMODEL + h * DH + dt * 16 + l15] =
            f2bf(O[dt][r] * iv);
    }
  };

  auto phase = [&](const bf16x8 (&qf)[2], int q0, int nt) {
    const int qw = q0 + wsub * 16;
    const int nsteps = (nt + 1) >> 1;
    for (int i = 0; i < nsteps; ++i) {
      const int u = 2 * i + team;
      stage(2 * i, 2 * i + 1, nt);
      __syncthreads();
      const int kv0 = u * 64;
      if (u < nt && kv0 <= qw + 15) tile(qf, kv0, qw);
      __syncthreads();
    }
    // ---- team merge (flash split-k combine) via sP reinterpreted as f32
    float* mb = (float*)&sP[0][0];
    if (team == 1) {
      float* bp = mb + wsub * 640;
#pragma unroll
      for (int dt = 0; dt < 2; ++dt)
#pragma unroll
        for (int r = 0; r < 4; ++r) bp[(dt * 4 + r) * 64 + lane] = O[dt][r];
      bp[512 + lane] = m_r;
      bp[576 + lane] = l_r;
    }
    __syncthreads();
    float a0 = 1.f, a1 = 0.f;
    if (team == 0) {
      float* bp = mb + wsub * 640;
      const float m1 = bp[512 + lane], l1 = bp[576 + lane];
      const float ms = fmaxf(m_r, m1);
      a0 = exp2f((m_r - ms) * CSC);
      a1 = exp2f((m1 - ms) * CSC);
      l_r = l_r * a0 + l1 * a1;
      m_r = ms;
#pragma unroll
      for (int r = 0; r < 4; ++r) {
        const float c0 = __shfl(a0, lg * 4 + r), c1 = __shfl(a1, lg * 4 + r);
        O[0][r] = O[0][r] * c0 + bp[r * 64 + lane] * c1;
        O[1][r] = O[1][r] * c0 + bp[(4 + r) * 64 + lane] * c1;
      }
    }
    __syncthreads();
    if (team == 1) {
      float* bp = mb + wsub * 512;
#pragma unroll
      for (int dt = 0; dt < 2; ++dt)
#pragma unroll
        for (int r = 0; r < 4; ++r) bp[(dt * 4 + r) * 64 + lane] = O[dt + 2][r];
    }
    __syncthreads();
    if (team == 0) {
      float* bp = mb + wsub * 512;
#pragma unroll
      for (int r = 0; r < 4; ++r) {
        const float c0 = __shfl(a0, lg * 4 + r), c1 = __shfl(a1, lg * 4 + r);
        O[2][r] = O[2][r] * c0 + bp[r * 64 + lane] * c1;
        O[3][r] = O[3][r] * c0 + bp[(4 + r) * 64 + lane] * c1;
      }
      writeOut(q0);
    }
    __syncthreads();
  };

  phase(qfA, q0a, ntA);
#pragma unroll
  for (int dt = 0; dt < 4; ++dt) O[dt] = f32x4{0.f, 0.f, 0.f, 0.f};
  m_r = -1e30f; l_r = 0.f;
  phase(qfB, q0b, ntB);
}

// ---------------------------------------------------------------------------
extern "C" void kernel_launch(void* const* d_in, const int* in_sizes, int n_in,
                              void* d_out, int out_size, void* d_ws, size_t ws_size,
                              hipStream_t stream) {
  const float* x  = (const float*)d_in[0];
  // d_in[1] = causal mask (tril) — structure known, not read
  const float* Wq = (const float*)d_in[2];
  const float* Wk = (const float*)d_in[3];
  const float* Wv = (const float*)d_in[4];
  const float* Wo = (const float*)d_in[5];
  float* out = (float*)d_out;

  unsigned short* ws = (unsigned short*)d_ws;
  const size_t MEL = (size_t)1024 * 1024;
  unsigned short* xb   = ws;            // 4M elems
  unsigned short* wqkv = xb + 4 * MEL;  // 3M (Wq|Wk|Wv rows)
  unsigned short* wo   = wqkv + 3 * MEL;// 1M
  unsigned short* qb   = wo + MEL;      // 4M  [bh][s][64]
  unsigned short* kb   = qb + 4 * MEL;  // 4M  [bh][s][64]
  unsigned short* vtb  = kb + 4 * MEL;  // 4M  [bh][64][s]
  unsigned short* attn = vtb + 4 * MEL; // 4M  [b*s][1024]

  cvt8<<<2048, 256, 0, stream>>>(x, xb, 524288);
  cvt8<<<512, 256, 0, stream>>>(Wq, wqkv, 131072);
  cvt8<<<512, 256, 0, stream>>>(Wk, wqkv + MEL, 131072);
  cvt8<<<512, 256, 0, stream>>>(Wv, wqkv + 2 * MEL, 131072);
  cvt8<<<512, 256, 0, stream>>>(Wo, wo, 131072);

  dim3 g1(3072 / 128, 4096 / 128);  // QKV projection
  gemm_bt<0><<<g1, 256, 0, stream>>>(xb, wqkv, DMODEL, qb, kb, vtb, nullptr);

  dim3 g2(16, BATCH * HEADS);  // attention: paired q-tiles + team kv-split
  attn_fwd<<<g2, 512, 0, stream>>>(qb, kb, vtb, attn);

  dim3 g3(1024 / 128, 4096 / 128);  // output projection
  gemm_bt<1><<<g3, 256, 0, stream>>>(attn, wo, DMODEL, nullptr, nullptr, nullptr, out);
}